// Round 6
// baseline (2372.003 us; speedup 1.0000x reference)
//
#include <hip/hip_runtime.h>
#include <hip/hip_bf16.h>

#define BN_EPS 1e-5f

static __device__ __forceinline__ unsigned short f2bf(float f) {
    unsigned u = __float_as_uint(f);
    unsigned r = (u + 0x7FFF + ((u >> 16) & 1)) >> 16;
    return (unsigned short)r;
}
static __device__ __forceinline__ float bf2f(unsigned short s) {
    return __uint_as_float((unsigned)s << 16);
}

// ---------------- degree histogram (per node) ----------------
__global__ void hist_kernel(const int* __restrict__ dst, int* __restrict__ cnt, int e) {
    int i = blockIdx.x * 256 + threadIdx.x;
    if (i < e) atomicAdd(&cnt[dst[i]], 1);
}

__global__ void dinv_kernel(const int* __restrict__ cnt, float* __restrict__ dinv, int n) {
    int i = blockIdx.x * 256 + threadIdx.x;
    if (i < n) dinv[i] = rsqrtf((float)(cnt[i] + 1));   // deg = indeg + self-loop >= 1
}

// ---------------- bucket counts: bcnt[b] = sum cnt[b*64 .. b*64+63] ---------
__global__ void bucket_sum(const int* __restrict__ cnt, int* __restrict__ bcnt,
                           int n, int nb) {
    int b = blockIdx.x * 4 + (threadIdx.x >> 6);
    int lane = threadIdx.x & 63;
    if (b >= nb) return;
    int i = b * 64 + lane;
    int v = (i < n) ? cnt[i] : 0;
#pragma unroll
    for (int off = 32; off > 0; off >>= 1) v += __shfl_down(v, off);
    if (lane == 0) bcnt[b] = v;
}

// ---------------- exclusive scan (3-pass, chunk = 1024) ----------------
#define SCAN_CHUNK 1024

__global__ void scan_block_sums(const int* __restrict__ cnt, int* __restrict__ bsums, int n) {
    __shared__ int sdata[256];
    int b = blockIdx.x, t = threadIdx.x;
    int base = b * SCAN_CHUNK;
    int s = 0;
    for (int i = t; i < SCAN_CHUNK; i += 256) {
        int idx = base + i;
        if (idx < n) s += cnt[idx];
    }
    sdata[t] = s;
    __syncthreads();
    for (int off = 128; off > 0; off >>= 1) {
        if (t < off) sdata[t] += sdata[t + off];
        __syncthreads();
    }
    if (t == 0) bsums[b] = sdata[0];
}

__global__ void scan_exclusive_bsums(int* __restrict__ bsums, int nb) {
    if (threadIdx.x == 0 && blockIdx.x == 0) {
        int acc = 0;
        for (int i = 0; i < nb; i++) { int v = bsums[i]; bsums[i] = acc; acc += v; }
    }
}

__global__ void scan_write(const int* __restrict__ cnt, const int* __restrict__ bsums,
                           int* __restrict__ row_start, int n) {
    __shared__ int sdata[256];
    int b = blockIdx.x, t = threadIdx.x;
    int base = b * SCAN_CHUNK + t * 4;
    int v0 = 0, v1 = 0, v2 = 0, v3 = 0;
    if (base + 0 < n) v0 = cnt[base + 0];
    if (base + 1 < n) v1 = cnt[base + 1];
    if (base + 2 < n) v2 = cnt[base + 2];
    if (base + 3 < n) v3 = cnt[base + 3];
    int tsum = v0 + v1 + v2 + v3;
    sdata[t] = tsum;
    __syncthreads();
    for (int off = 1; off < 256; off <<= 1) {       // inclusive Hillis-Steele
        int x = (t >= off) ? sdata[t - off] : 0;
        __syncthreads();
        sdata[t] += x;
        __syncthreads();
    }
    int excl = sdata[t] - tsum + bsums[b];
    if (base + 0 < n) row_start[base + 0] = excl;
    if (base + 1 < n) row_start[base + 1] = excl + v0;
    if (base + 2 < n) row_start[base + 2] = excl + v0 + v1;
    if (base + 3 < n) row_start[base + 3] = excl + v0 + v1 + v2;
    if (n - 1 >= base && n - 1 < base + 4)          // finalize total
        row_start[n] = excl + v0 + v1 + v2 + v3;
}

// ---------------- pass 1: edges -> bucket-major {src|dloc<<17, val} --------
// bucket = dst>>6; per-bucket cursor; writes fill each bucket region densely.
__global__ void pass1_kernel(const int* __restrict__ src, const int* __restrict__ dst,
                             const int* __restrict__ bstart, int* __restrict__ bcur,
                             const float* __restrict__ dinv,
                             int2* __restrict__ ebuf, int e) {
    int i = blockIdx.x * 256 + threadIdx.x;
    if (i >= e) return;
    int s = src[i], d = dst[i];
    int b = d >> 6;
    int pos = bstart[b] + atomicAdd(&bcur[b], 1);
    ebuf[pos] = make_int2(s | ((d & 63) << 17), __float_as_int(dinv[s] * dinv[d]));
}

// ---------------- dense linear: outbf[N,64] = in[N,K] @ w[K,64] (bf16 out) --
template<int K>
__global__ __launch_bounds__(256) void lin2(const float* __restrict__ in,
                                            const float* __restrict__ w,
                                            unsigned short* __restrict__ outbf, int n) {
    constexpr int XSS = K + 4;
    __shared__ float xs[64 * XSS];
    __shared__ float ws[K * 64];
    int t = threadIdx.x;
    int row0 = blockIdx.x * 64;
    int nrows = n - row0; if (nrows > 64) nrows = 64;

    {
        const float4* w4 = (const float4*)w;
        float4* ws4 = (float4*)ws;
#pragma unroll
        for (int idx = t; idx < K * 16; idx += 256) ws4[idx] = w4[idx];
    }
    {
        const float4* in4 = (const float4*)(in + (size_t)row0 * K);
        int total4 = nrows * (K / 4);
        for (int idx = t; idx < total4; idx += 256) {
            int r = idx / (K / 4), kk = idx - r * (K / 4);
            float4 v = in4[idx];
            *(float4*)&xs[r * XSS + kk * 4] = v;
        }
    }
    __syncthreads();

    int cg = t & 15;
    int rg = t >> 4;
    float acc[4][4];
#pragma unroll
    for (int r = 0; r < 4; r++)
#pragma unroll
        for (int c = 0; c < 4; c++) acc[r][c] = 0.f;

    const float* xbase = &xs[rg * 4 * XSS];
    const float* wbase = &ws[cg * 4];
#pragma unroll 4
    for (int k = 0; k < K; k += 4) {
        float4 a0 = *(const float4*)&xbase[0 * XSS + k];
        float4 a1 = *(const float4*)&xbase[1 * XSS + k];
        float4 a2 = *(const float4*)&xbase[2 * XSS + k];
        float4 a3 = *(const float4*)&xbase[3 * XSS + k];
        float4 w0 = *(const float4*)&wbase[(k + 0) * 64];
        float4 w1 = *(const float4*)&wbase[(k + 1) * 64];
        float4 w2 = *(const float4*)&wbase[(k + 2) * 64];
        float4 w3 = *(const float4*)&wbase[(k + 3) * 64];
#pragma unroll
        for (int r = 0; r < 4; r++) {
            float4 a = (r == 0) ? a0 : (r == 1) ? a1 : (r == 2) ? a2 : a3;
            acc[r][0] += a.x * w0.x + a.y * w1.x + a.z * w2.x + a.w * w3.x;
            acc[r][1] += a.x * w0.y + a.y * w1.y + a.z * w2.y + a.w * w3.y;
            acc[r][2] += a.x * w0.z + a.y * w1.z + a.z * w2.z + a.w * w3.z;
            acc[r][3] += a.x * w0.w + a.y * w1.w + a.z * w2.w + a.w * w3.w;
        }
    }
#pragma unroll
    for (int r = 0; r < 4; r++) {
        int row = rg * 4 + r;
        if (row < nrows) {
            ushort4 v;
            v.x = f2bf(acc[r][0]); v.y = f2bf(acc[r][1]);
            v.z = f2bf(acc[r][2]); v.w = f2bf(acc[r][3]);
            *(ushort4*)&outbf[(size_t)(row0 + row) * 64 + cg * 4] = v;
        }
    }
}

// ---------------- bucket aggregation + bias + BN + ReLU ----------------
// one block per 64-node bucket; LDS fp32 accumulator [64 rows x 64 feats];
// edges staged in LDS; per edge: coalesced bf16 row gather + ds_add_f32.
#define ECH 1024
__global__ __launch_bounds__(256) void agg_bucket(
        const unsigned short* __restrict__ hlin, const int* __restrict__ bstart,
        const int2* __restrict__ ebuf, const float* __restrict__ dinv,
        const float* __restrict__ bias, const float* __restrict__ gam,
        const float* __restrict__ bet, const float* __restrict__ mu,
        const float* __restrict__ var,
        float* __restrict__ out, int n) {
    __shared__ float acc[64 * 64];      // 16 KB
    __shared__ int2 eb[ECH];            // 8 KB
    int b = blockIdx.x;
    int t = threadIdx.x;
    int lane = t & 63, w = t >> 6;
    int node0 = b * 64;
    int nrows = n - node0; if (nrows > 64) nrows = 64;

    // init with self-loop contribution
    for (int r = w; r < nrows; r += 4) {
        int i = node0 + r;
        float di = dinv[i];
        acc[r * 64 + lane] = di * di * bf2f(hlin[(size_t)i * 64 + lane]);
    }
    __syncthreads();

    int e0 = bstart[b], e1 = bstart[b + 1];
    for (int j0 = e0; j0 < e1; j0 += ECH) {
        int m = e1 - j0; if (m > ECH) m = ECH;
        for (int k = t; k < m; k += 256) eb[k] = ebuf[j0 + k];
        __syncthreads();
        for (int k = w; k < m; k += 4) {
            int2 e = eb[k];
            int s = e.x & 0x1FFFF;
            int dloc = e.x >> 17;
            float v = __int_as_float(e.y);
            float h = bf2f(hlin[(size_t)s * 64 + lane]);
            atomicAdd(&acc[dloc * 64 + lane], v * h);   // ds_add_f32
        }
        __syncthreads();
    }

    float scale = gam[lane] * rsqrtf(var[lane] + BN_EPS);
    for (int r = w; r < nrows; r += 4) {
        int i = node0 + r;
        float val = (acc[r * 64 + lane] + bias[lane] - mu[lane]) * scale + bet[lane];
        out[(size_t)i * 64 + lane] = val > 0.f ? val : 0.f;
    }
}

// ---------------- pool stage 1: node-parallel segmented sum ----------------
#define POOL_CHUNK 64
__global__ __launch_bounds__(256) void pool_kernel(const float* __restrict__ h,
                                                   const int* __restrict__ batch,
                                                   float* __restrict__ pooled, int n) {
    int wid = blockIdx.x * 4 + (threadIdx.x >> 6);
    int lane = threadIdx.x & 63;
    int start = wid * POOL_CHUNK;
    if (start >= n) return;
    int end = start + POOL_CHUNK; if (end > n) end = n;
    int cur = batch[start];
    float acc = 0.f;
    for (int i = start; i < end; i++) {
        int b = batch[i];
        if (b != cur) {
            atomicAdd(&pooled[(size_t)cur * 64 + lane], acc);
            acc = 0.f; cur = b;
        }
        acc += h[(size_t)i * 64 + lane];
    }
    atomicAdd(&pooled[(size_t)cur * 64 + lane], acc);
}

// ---------------- pool stage 2: tiny MLP per graph ----------------
__global__ void mlp_kernel(const float* __restrict__ pooled,
                           const float* __restrict__ l1w, const float* __restrict__ l1b,
                           const float* __restrict__ l2w, const float* __restrict__ l2b,
                           float* __restrict__ out) {
    int g = blockIdx.x;
    int lane = threadIdx.x;
    __shared__ float p[64];
    __shared__ float h1[32];
    p[lane] = pooled[(size_t)g * 64 + lane];
    __syncthreads();
    if (lane < 32) {
        float a = l1b[lane];
#pragma unroll 8
        for (int k = 0; k < 64; k++) a += p[k] * l1w[k * 32 + lane];
        h1[lane] = a > 0.f ? a : 0.f;
    }
    __syncthreads();
    if (lane < 2) {
        float a = l2b[lane];
#pragma unroll 8
        for (int j = 0; j < 32; j++) a += h1[j] * l2w[j * 2 + lane];
        out[g * 2 + lane] = a;
    }
}

extern "C" void kernel_launch(void* const* d_in, const int* in_sizes, int n_in,
                              void* d_out, int out_size, void* d_ws, size_t ws_size,
                              hipStream_t stream) {
    const float* x     = (const float*)d_in[0];
    const int*   ei    = (const int*)d_in[1];
    const int*   batch = (const int*)d_in[2];
    const float* w0 = (const float*)d_in[3];
    const float* b0 = (const float*)d_in[4];
    const float* w1 = (const float*)d_in[5];
    const float* b1 = (const float*)d_in[6];
    const float* w2 = (const float*)d_in[7];
    const float* b2 = (const float*)d_in[8];
    const float* g0 = (const float*)d_in[9];
    const float* be0 = (const float*)d_in[10];
    const float* m0 = (const float*)d_in[11];
    const float* v0 = (const float*)d_in[12];
    const float* g1 = (const float*)d_in[13];
    const float* be1 = (const float*)d_in[14];
    const float* m1 = (const float*)d_in[15];
    const float* v1 = (const float*)d_in[16];
    const float* g2 = (const float*)d_in[17];
    const float* be2 = (const float*)d_in[18];
    const float* m2 = (const float*)d_in[19];
    const float* v2 = (const float*)d_in[20];
    const float* l1w = (const float*)d_in[21];
    const float* l1b = (const float*)d_in[22];
    const float* l2w = (const float*)d_in[23];
    const float* l2b = (const float*)d_in[24];
    float* out = (float*)d_out;

    const int N = in_sizes[2];
    const int E = in_sizes[1] / 2;
    const int G = out_size / 2;
    const int B = (N + 63) / 64;          // buckets of 64 nodes

    const int* src = ei;
    const int* dst = ei + E;

    // workspace layout
    char* p = (char*)d_ws;
    auto alloc = [&](size_t bytes) -> void* {
        void* r = (void*)p;
        p += (bytes + 255) & ~(size_t)255;
        return r;
    };
    float* dinvp    = (float*)alloc((size_t)N * 4);
    int*   cnt      = (int*)alloc((size_t)N * 4);
    int*   bcnt     = (int*)alloc((size_t)B * 4);
    int*   bstart   = (int*)alloc((size_t)(B + 1) * 4);
    int*   bcur     = (int*)alloc((size_t)B * 4);
    int    NB2      = (B + SCAN_CHUNK - 1) / SCAN_CHUNK;
    int*   bsums    = (int*)alloc((size_t)NB2 * 4);
    int2*  ebuf     = (int2*)alloc((size_t)E * 8);
    unsigned short* h_a = (unsigned short*)alloc((size_t)N * 64 * 2);  // bf16 lin out
    float* h_b      = (float*)alloc((size_t)N * 64 * 4);               // fp32 agg out
    float* pooled   = (float*)alloc((size_t)G * 64 * 4);
    (void)ws_size;

    // ---- graph preprocessing ----
    hipMemsetAsync(cnt, 0, (size_t)N * 4, stream);
    hipMemsetAsync(bcur, 0, (size_t)B * 4, stream);
    hipMemsetAsync(pooled, 0, (size_t)G * 64 * 4, stream);
    hist_kernel<<<(E + 255) / 256, 256, 0, stream>>>(dst, cnt, E);
    dinv_kernel<<<(N + 255) / 256, 256, 0, stream>>>(cnt, dinvp, N);
    bucket_sum<<<(B + 3) / 4, 256, 0, stream>>>(cnt, bcnt, N, B);
    scan_block_sums<<<NB2, 256, 0, stream>>>(bcnt, bsums, B);
    scan_exclusive_bsums<<<1, 64, 0, stream>>>(bsums, NB2);
    scan_write<<<NB2, 256, 0, stream>>>(bcnt, bsums, bstart, B);
    pass1_kernel<<<(E + 255) / 256, 256, 0, stream>>>(src, dst, bstart, bcur, dinvp,
                                                      ebuf, E);

    const int lblk = (N + 63) / 64;
    // ---- layer 0 ----
    lin2<128><<<lblk, 256, 0, stream>>>(x, w0, h_a, N);
    agg_bucket<<<B, 256, 0, stream>>>(h_a, bstart, ebuf, dinvp,
                                      b0, g0, be0, m0, v0, h_b, N);
    // ---- layer 1 ----
    lin2<64><<<lblk, 256, 0, stream>>>(h_b, w1, h_a, N);
    agg_bucket<<<B, 256, 0, stream>>>(h_a, bstart, ebuf, dinvp,
                                      b1, g1, be1, m1, v1, h_b, N);
    // ---- layer 2 ----
    lin2<64><<<lblk, 256, 0, stream>>>(h_b, w2, h_a, N);
    agg_bucket<<<B, 256, 0, stream>>>(h_a, bstart, ebuf, dinvp,
                                      b2, g2, be2, m2, v2, h_b, N);
    // ---- pool + MLP ----
    const int pwaves = (N + POOL_CHUNK - 1) / POOL_CHUNK;
    pool_kernel<<<(pwaves + 3) / 4, 256, 0, stream>>>(h_b, batch, pooled, N);
    mlp_kernel<<<G, 64, 0, stream>>>(pooled, l1w, l1b, l2w, l2b, out);
}

// Round 7
// 574.096 us; speedup vs baseline: 4.1317x; 4.1317x over previous
//
#include <hip/hip_runtime.h>
#include <hip/hip_bf16.h>

#define BN_EPS 1e-5f

static __device__ __forceinline__ unsigned short f2bf(float f) {
    unsigned u = __float_as_uint(f);
    unsigned r = (u + 0x7FFF + ((u >> 16) & 1)) >> 16;
    return (unsigned short)r;
}
static __device__ __forceinline__ float bf2f(unsigned short s) {
    return __uint_as_float((unsigned)s << 16);
}
__device__ __forceinline__ int pad8i(int c) { return (c + 7) & ~7; }

// ---------------- degree histogram ----------------
__global__ void hist_kernel(const int* __restrict__ dst, int* __restrict__ cnt, int e) {
    int i = blockIdx.x * 256 + threadIdx.x;
    if (i < e) atomicAdd(&cnt[dst[i]], 1);
}

__global__ void dinv_kernel(const int* __restrict__ cnt, float* __restrict__ dinv, int n) {
    int i = blockIdx.x * 256 + threadIdx.x;
    if (i < n) dinv[i] = rsqrtf((float)(cnt[i] + 1));   // deg = indeg + self-loop >= 1
}

// ---------------- exclusive scan over PADDED counts (3-pass, chunk = 1024) ----
#define SCAN_CHUNK 1024

__global__ void scan_block_sums(const int* __restrict__ cnt, int* __restrict__ bsums, int n) {
    __shared__ int sdata[256];
    int b = blockIdx.x, t = threadIdx.x;
    int base = b * SCAN_CHUNK;
    int s = 0;
    for (int i = t; i < SCAN_CHUNK; i += 256) {
        int idx = base + i;
        if (idx < n) s += pad8i(cnt[idx]);
    }
    sdata[t] = s;
    __syncthreads();
    for (int off = 128; off > 0; off >>= 1) {
        if (t < off) sdata[t] += sdata[t + off];
        __syncthreads();
    }
    if (t == 0) bsums[b] = sdata[0];
}

__global__ void scan_exclusive_bsums(int* __restrict__ bsums, int nb) {
    if (threadIdx.x == 0 && blockIdx.x == 0) {
        int acc = 0;
        for (int i = 0; i < nb; i++) { int v = bsums[i]; bsums[i] = acc; acc += v; }
    }
}

__global__ void scan_write(const int* __restrict__ cnt, const int* __restrict__ bsums,
                           int* __restrict__ row_start, int n) {
    __shared__ int sdata[256];
    int b = blockIdx.x, t = threadIdx.x;
    int base = b * SCAN_CHUNK + t * 4;
    int v0 = 0, v1 = 0, v2 = 0, v3 = 0;
    if (base + 0 < n) v0 = pad8i(cnt[base + 0]);
    if (base + 1 < n) v1 = pad8i(cnt[base + 1]);
    if (base + 2 < n) v2 = pad8i(cnt[base + 2]);
    if (base + 3 < n) v3 = pad8i(cnt[base + 3]);
    int tsum = v0 + v1 + v2 + v3;
    sdata[t] = tsum;
    __syncthreads();
    for (int off = 1; off < 256; off <<= 1) {       // inclusive Hillis-Steele
        int x = (t >= off) ? sdata[t - off] : 0;
        __syncthreads();
        sdata[t] += x;
        __syncthreads();
    }
    int excl = sdata[t] - tsum + bsums[b];
    if (base + 0 < n) row_start[base + 0] = excl;
    if (base + 1 < n) row_start[base + 1] = excl + v0;
    if (base + 2 < n) row_start[base + 2] = excl + v0 + v1;
    if (base + 3 < n) row_start[base + 3] = excl + v0 + v1 + v2;
    if (n - 1 >= base && n - 1 < base + 4)          // finalize total (padded end)
        row_start[n] = excl + v0 + v1 + v2 + v3;
}

// ---------------- dense fill: csr[j] = sentinel (pads -> zero row) ---------
__global__ void fill_kernel(int* __restrict__ csr, int val, int m4) {
    int i = blockIdx.x * 256 + threadIdx.x;
    if (i < m4) ((int4*)csr)[i] = make_int4(val, val, val, val);
}

// ---------------- CSR scatter: src index only (4 B/edge) -------------------
__global__ void scatter_kernel(const int* __restrict__ src, const int* __restrict__ dst,
                               const int* __restrict__ row_start, int* __restrict__ cursor,
                               int* __restrict__ csr, int e) {
    int i = blockIdx.x * 256 + threadIdx.x;
    if (i >= e) return;
    int s = src[i], d = dst[i];
    int pos = row_start[d] + atomicAdd(&cursor[d], 1);
    csr[pos] = s;
}

// ---------------- dense linear: hs[N,64] = dinv[r] * (in[N,K] @ w[K,64]) ----
// bf16 out; block = 256 thr, 64-row tile; 4x4 micro-tile per thread.
template<int K>
__global__ __launch_bounds__(256) void lin2(const float* __restrict__ in,
                                            const float* __restrict__ w,
                                            const float* __restrict__ dinv,
                                            unsigned short* __restrict__ outbf, int n) {
    constexpr int XSS = K + 4;
    __shared__ float xs[64 * XSS];
    __shared__ float ws[K * 64];
    int t = threadIdx.x;
    int row0 = blockIdx.x * 64;
    int nrows = n - row0; if (nrows > 64) nrows = 64;

    {
        const float4* w4 = (const float4*)w;
        float4* ws4 = (float4*)ws;
#pragma unroll
        for (int idx = t; idx < K * 16; idx += 256) ws4[idx] = w4[idx];
    }
    {
        const float4* in4 = (const float4*)(in + (size_t)row0 * K);
        int total4 = nrows * (K / 4);
        for (int idx = t; idx < total4; idx += 256) {
            int r = idx / (K / 4), kk = idx - r * (K / 4);
            float4 v = in4[idx];
            *(float4*)&xs[r * XSS + kk * 4] = v;
        }
    }
    __syncthreads();

    int cg = t & 15;
    int rg = t >> 4;
    float acc[4][4];
#pragma unroll
    for (int r = 0; r < 4; r++)
#pragma unroll
        for (int c = 0; c < 4; c++) acc[r][c] = 0.f;

    const float* xbase = &xs[rg * 4 * XSS];
    const float* wbase = &ws[cg * 4];
#pragma unroll 4
    for (int k = 0; k < K; k += 4) {
        float4 a0 = *(const float4*)&xbase[0 * XSS + k];
        float4 a1 = *(const float4*)&xbase[1 * XSS + k];
        float4 a2 = *(const float4*)&xbase[2 * XSS + k];
        float4 a3 = *(const float4*)&xbase[3 * XSS + k];
        float4 w0 = *(const float4*)&wbase[(k + 0) * 64];
        float4 w1 = *(const float4*)&wbase[(k + 1) * 64];
        float4 w2 = *(const float4*)&wbase[(k + 2) * 64];
        float4 w3 = *(const float4*)&wbase[(k + 3) * 64];
#pragma unroll
        for (int r = 0; r < 4; r++) {
            float4 a = (r == 0) ? a0 : (r == 1) ? a1 : (r == 2) ? a2 : a3;
            acc[r][0] += a.x * w0.x + a.y * w1.x + a.z * w2.x + a.w * w3.x;
            acc[r][1] += a.x * w0.y + a.y * w1.y + a.z * w2.y + a.w * w3.y;
            acc[r][2] += a.x * w0.z + a.y * w1.z + a.z * w2.z + a.w * w3.z;
            acc[r][3] += a.x * w0.w + a.y * w1.w + a.z * w2.w + a.w * w3.w;
        }
    }
#pragma unroll
    for (int r = 0; r < 4; r++) {
        int row = rg * 4 + r;
        if (row < nrows) {
            float dv = dinv[row0 + row];
            ushort4 v;
            v.x = f2bf(acc[r][0] * dv); v.y = f2bf(acc[r][1] * dv);
            v.z = f2bf(acc[r][2] * dv); v.w = f2bf(acc[r][3] * dv);
            *(ushort4*)&outbf[(size_t)(row0 + row) * 64 + cg * 4] = v;
        }
    }
}

// ---------------- aggregation + bias + BN + ReLU ----------------
// one wave per node; hs rows pre-scaled by dinv[s]; csr = src only (padded
// to x8 with sentinel N whose row is zero). agg_i = dinv[i]*(self + sum).
__global__ __launch_bounds__(256) void agg_kernel(
        const unsigned short* __restrict__ hs, const int* __restrict__ row_start,
        const int* __restrict__ csr, const float* __restrict__ dinv,
        const float* __restrict__ bias, const float* __restrict__ gam,
        const float* __restrict__ bet, const float* __restrict__ mu,
        const float* __restrict__ var,
        float* __restrict__ out, int n) {
    int i = blockIdx.x * 4 + (threadIdx.x >> 6);
    int lane = threadIdx.x & 63;
    if (i >= n) return;
    float acc = bf2f(hs[(size_t)i * 64 + lane]);   // self-loop term (pre-scaled)
    int rs = row_start[i], re = row_start[i + 1];  // multiples of 8
    for (int j = rs; j < re; j += 8) {
        int4 c0 = *(const int4*)&csr[j];
        int4 c1 = *(const int4*)&csr[j + 4];
        float h0 = bf2f(hs[(size_t)c0.x * 64 + lane]);
        float h1 = bf2f(hs[(size_t)c0.y * 64 + lane]);
        float h2 = bf2f(hs[(size_t)c0.z * 64 + lane]);
        float h3 = bf2f(hs[(size_t)c0.w * 64 + lane]);
        float h4 = bf2f(hs[(size_t)c1.x * 64 + lane]);
        float h5 = bf2f(hs[(size_t)c1.y * 64 + lane]);
        float h6 = bf2f(hs[(size_t)c1.z * 64 + lane]);
        float h7 = bf2f(hs[(size_t)c1.w * 64 + lane]);
        acc += ((h0 + h1) + (h2 + h3)) + ((h4 + h5) + (h6 + h7));
    }
    float agg = acc * dinv[i];
    float scale = gam[lane] * rsqrtf(var[lane] + BN_EPS);
    float r = (agg + bias[lane] - mu[lane]) * scale + bet[lane];
    out[(size_t)i * 64 + lane] = r > 0.f ? r : 0.f;
}

// ---------------- pool stage 1: node-parallel segmented sum ----------------
#define POOL_CHUNK 64
__global__ __launch_bounds__(256) void pool_kernel(const float* __restrict__ h,
                                                   const int* __restrict__ batch,
                                                   float* __restrict__ pooled, int n) {
    int wid = blockIdx.x * 4 + (threadIdx.x >> 6);
    int lane = threadIdx.x & 63;
    int start = wid * POOL_CHUNK;
    if (start >= n) return;
    int end = start + POOL_CHUNK; if (end > n) end = n;
    int cur = batch[start];
    float acc = 0.f;
    for (int i = start; i < end; i++) {
        int b = batch[i];
        if (b != cur) {
            atomicAdd(&pooled[(size_t)cur * 64 + lane], acc);
            acc = 0.f; cur = b;
        }
        acc += h[(size_t)i * 64 + lane];
    }
    atomicAdd(&pooled[(size_t)cur * 64 + lane], acc);
}

// ---------------- pool stage 2: tiny MLP per graph ----------------
__global__ void mlp_kernel(const float* __restrict__ pooled,
                           const float* __restrict__ l1w, const float* __restrict__ l1b,
                           const float* __restrict__ l2w, const float* __restrict__ l2b,
                           float* __restrict__ out) {
    int g = blockIdx.x;
    int lane = threadIdx.x;
    __shared__ float p[64];
    __shared__ float h1[32];
    p[lane] = pooled[(size_t)g * 64 + lane];
    __syncthreads();
    if (lane < 32) {
        float a = l1b[lane];
#pragma unroll 8
        for (int k = 0; k < 64; k++) a += p[k] * l1w[k * 32 + lane];
        h1[lane] = a > 0.f ? a : 0.f;
    }
    __syncthreads();
    if (lane < 2) {
        float a = l2b[lane];
#pragma unroll 8
        for (int j = 0; j < 32; j++) a += h1[j] * l2w[j * 2 + lane];
        out[g * 2 + lane] = a;
    }
}

extern "C" void kernel_launch(void* const* d_in, const int* in_sizes, int n_in,
                              void* d_out, int out_size, void* d_ws, size_t ws_size,
                              hipStream_t stream) {
    const float* x     = (const float*)d_in[0];
    const int*   ei    = (const int*)d_in[1];
    const int*   batch = (const int*)d_in[2];
    const float* w0 = (const float*)d_in[3];
    const float* b0 = (const float*)d_in[4];
    const float* w1 = (const float*)d_in[5];
    const float* b1 = (const float*)d_in[6];
    const float* w2 = (const float*)d_in[7];
    const float* b2 = (const float*)d_in[8];
    const float* g0 = (const float*)d_in[9];
    const float* be0 = (const float*)d_in[10];
    const float* m0 = (const float*)d_in[11];
    const float* v0 = (const float*)d_in[12];
    const float* g1 = (const float*)d_in[13];
    const float* be1 = (const float*)d_in[14];
    const float* m1 = (const float*)d_in[15];
    const float* v1 = (const float*)d_in[16];
    const float* g2 = (const float*)d_in[17];
    const float* be2 = (const float*)d_in[18];
    const float* m2 = (const float*)d_in[19];
    const float* v2 = (const float*)d_in[20];
    const float* l1w = (const float*)d_in[21];
    const float* l1b = (const float*)d_in[22];
    const float* l2w = (const float*)d_in[23];
    const float* l2b = (const float*)d_in[24];
    float* out = (float*)d_out;

    const int N = in_sizes[2];
    const int E = in_sizes[1] / 2;
    const int G = out_size / 2;

    const int* src = ei;
    const int* dst = ei + E;

    // workspace layout
    char* p = (char*)d_ws;
    auto alloc = [&](size_t bytes) -> void* {
        void* r = (void*)p;
        p += (bytes + 255) & ~(size_t)255;
        return r;
    };
    const size_t CSR_CAP = ((size_t)E + 8 * (size_t)N + 3) & ~(size_t)3;
    float* dinvp    = (float*)alloc((size_t)N * 4);
    int*   cnt      = (int*)alloc((size_t)N * 4);
    int*   row_start= (int*)alloc((size_t)(N + 1) * 4);
    int*   cursor   = (int*)alloc((size_t)N * 4);
    int    NB       = (N + SCAN_CHUNK - 1) / SCAN_CHUNK;
    int*   bsums    = (int*)alloc((size_t)NB * 4);
    int*   csr      = (int*)alloc(CSR_CAP * 4);
    unsigned short* h_a = (unsigned short*)alloc((size_t)(N + 1) * 64 * 2); // +sentinel row
    float* h_b      = (float*)alloc((size_t)N * 64 * 4);
    float* pooled   = (float*)alloc((size_t)G * 64 * 4);
    (void)ws_size;

    // ---- graph preprocessing ----
    hipMemsetAsync(cnt, 0, (size_t)N * 4, stream);
    hipMemsetAsync(cursor, 0, (size_t)N * 4, stream);
    hipMemsetAsync(pooled, 0, (size_t)G * 64 * 4, stream);
    hipMemsetAsync(h_a + (size_t)N * 64, 0, 64 * 2, stream);   // zero sentinel row
    hist_kernel<<<(E + 255) / 256, 256, 0, stream>>>(dst, cnt, E);
    dinv_kernel<<<(N + 255) / 256, 256, 0, stream>>>(cnt, dinvp, N);
    scan_block_sums<<<NB, 256, 0, stream>>>(cnt, bsums, N);
    scan_exclusive_bsums<<<1, 64, 0, stream>>>(bsums, NB);
    scan_write<<<NB, 256, 0, stream>>>(cnt, bsums, row_start, N);
    {   // fill csr with sentinel N so pad entries read the zero row
        int m4 = (int)(CSR_CAP / 4);
        fill_kernel<<<(m4 + 255) / 256, 256, 0, stream>>>(csr, N, m4);
    }
    scatter_kernel<<<(E + 255) / 256, 256, 0, stream>>>(src, dst, row_start, cursor, csr, E);

    const int nblk = (N + 3) / 4;
    const int lblk = (N + 63) / 64;
    // ---- layer 0 ----
    lin2<128><<<lblk, 256, 0, stream>>>(x, w0, dinvp, h_a, N);
    agg_kernel<<<nblk, 256, 0, stream>>>(h_a, row_start, csr, dinvp,
                                         b0, g0, be0, m0, v0, h_b, N);
    // ---- layer 1 ----
    lin2<64><<<lblk, 256, 0, stream>>>(h_b, w1, dinvp, h_a, N);
    agg_kernel<<<nblk, 256, 0, stream>>>(h_a, row_start, csr, dinvp,
                                         b1, g1, be1, m1, v1, h_b, N);
    // ---- layer 2 ----
    lin2<64><<<lblk, 256, 0, stream>>>(h_b, w2, dinvp, h_a, N);
    agg_kernel<<<nblk, 256, 0, stream>>>(h_a, row_start, csr, dinvp,
                                         b2, g2, be2, m2, v2, h_b, N);
    // ---- pool + MLP ----
    const int pwaves = (N + POOL_CHUNK - 1) / POOL_CHUNK;
    pool_kernel<<<(pwaves + 3) / 4, 256, 0, stream>>>(h_b, batch, pooled, N);
    mlp_kernel<<<G, 64, 0, stream>>>(pooled, l1w, l1b, l2w, l2b, out);
}

// Round 8
// 519.376 us; speedup vs baseline: 4.5670x; 1.1054x over previous
//
#include <hip/hip_runtime.h>
#include <hip/hip_bf16.h>

#define BN_EPS 1e-5f

static __device__ __forceinline__ unsigned short f2bf(float f) {
    unsigned u = __float_as_uint(f);
    unsigned r = (u + 0x7FFF + ((u >> 16) & 1)) >> 16;
    return (unsigned short)r;
}
static __device__ __forceinline__ float bf2f(unsigned short s) {
    return __uint_as_float((unsigned)s << 16);
}
__device__ __forceinline__ int pad8i(int c) { return (c + 7) & ~7; }

#define BIN_SHIFT 9
#define BIN_NODES 512
#define P1_CHUNK 8192
#define IMG_CAP 12288

// ---------------- degree histogram ----------------
__global__ void hist_kernel(const int* __restrict__ dst, int* __restrict__ cnt, int e) {
    int i = blockIdx.x * 256 + threadIdx.x;
    if (i < e) atomicAdd(&cnt[dst[i]], 1);
}

__global__ void dinv_kernel(const int* __restrict__ cnt, float* __restrict__ dinv, int n) {
    int i = blockIdx.x * 256 + threadIdx.x;
    if (i < n) dinv[i] = rsqrtf((float)(cnt[i] + 1));   // deg = indeg + self-loop >= 1
}

// ---------------- exclusive scan over PADDED counts (3-pass, chunk = 1024) ----
#define SCAN_CHUNK 1024

__global__ void scan_block_sums(const int* __restrict__ cnt, int* __restrict__ bsums, int n) {
    __shared__ int sdata[256];
    int b = blockIdx.x, t = threadIdx.x;
    int base = b * SCAN_CHUNK;
    int s = 0;
    for (int i = t; i < SCAN_CHUNK; i += 256) {
        int idx = base + i;
        if (idx < n) s += pad8i(cnt[idx]);
    }
    sdata[t] = s;
    __syncthreads();
    for (int off = 128; off > 0; off >>= 1) {
        if (t < off) sdata[t] += sdata[t + off];
        __syncthreads();
    }
    if (t == 0) bsums[b] = sdata[0];
}

__global__ void scan_exclusive_bsums(int* __restrict__ bsums, int nb) {
    if (threadIdx.x == 0 && blockIdx.x == 0) {
        int acc = 0;
        for (int i = 0; i < nb; i++) { int v = bsums[i]; bsums[i] = acc; acc += v; }
    }
}

__global__ void scan_write(const int* __restrict__ cnt, const int* __restrict__ bsums,
                           int* __restrict__ row_start, int n) {
    __shared__ int sdata[256];
    int b = blockIdx.x, t = threadIdx.x;
    int base = b * SCAN_CHUNK + t * 4;
    int v0 = 0, v1 = 0, v2 = 0, v3 = 0;
    if (base + 0 < n) v0 = pad8i(cnt[base + 0]);
    if (base + 1 < n) v1 = pad8i(cnt[base + 1]);
    if (base + 2 < n) v2 = pad8i(cnt[base + 2]);
    if (base + 3 < n) v3 = pad8i(cnt[base + 3]);
    int tsum = v0 + v1 + v2 + v3;
    sdata[t] = tsum;
    __syncthreads();
    for (int off = 1; off < 256; off <<= 1) {       // inclusive Hillis-Steele
        int x = (t >= off) ? sdata[t - off] : 0;
        __syncthreads();
        sdata[t] += x;
        __syncthreads();
    }
    int excl = sdata[t] - tsum + bsums[b];
    if (base + 0 < n) row_start[base + 0] = excl;
    if (base + 1 < n) row_start[base + 1] = excl + v0;
    if (base + 2 < n) row_start[base + 2] = excl + v0 + v1;
    if (base + 3 < n) row_start[base + 3] = excl + v0 + v1 + v2;
    if (n - 1 >= base && n - 1 < base + 4)          // finalize total (padded end)
        row_start[n] = excl + v0 + v1 + v2 + v3;
}

// ---------------- bin counts (sum of cnt over 512-node bins) ---------------
__global__ void binsum_kernel(const int* __restrict__ cnt, int* __restrict__ bincnt,
                              int n, int nbins) {
    int b = blockIdx.x * 4 + (threadIdx.x >> 6);
    int lane = threadIdx.x & 63;
    if (b >= nbins) return;
    int s = 0;
#pragma unroll
    for (int k = 0; k < BIN_NODES; k += 64) {
        int i = b * BIN_NODES + k + lane;
        if (i < n) s += cnt[i];
    }
#pragma unroll
    for (int off = 32; off > 0; off >>= 1) s += __shfl_down(s, off);
    if (lane == 0) bincnt[b] = s;
}

__global__ void scan_small(const int* __restrict__ in, int* __restrict__ out, int m) {
    if (threadIdx.x == 0 && blockIdx.x == 0) {
        int a = 0;
        for (int i = 0; i < m; i++) { out[i] = a; a += in[i]; }
        out[m] = a;
    }
}

// ---------------- dense fill: csr = sentinel (pads / fallback) -------------
__global__ void fill_kernel(int* __restrict__ csr, int val, int m4) {
    int i = blockIdx.x * 256 + threadIdx.x;
    if (i < m4) ((int4*)csr)[i] = make_int4(val, val, val, val);
}

// ---------------- phase 1: partition edges into 512-node bins --------------
// per block: LDS hist over an 8192-edge chunk -> one global atomic per
// (block,bin) -> ranked dense appends of packed 4 B entries.
__global__ __launch_bounds__(256) void phase1_kernel(
        const int* __restrict__ src, const int* __restrict__ dst,
        const int* __restrict__ bstart_e, int* __restrict__ bincur,
        int* __restrict__ ebuf, int e, int nbins) {
    __shared__ int hist[256], base[256], cur[256];
    int t = threadIdx.x;
    int c0 = blockIdx.x * P1_CHUNK;
    int iend = c0 + P1_CHUNK; if (iend > e) iend = e;
    hist[t] = 0;
    __syncthreads();
    for (int i = c0 + t; i < iend; i += 256)
        atomicAdd(&hist[dst[i] >> BIN_SHIFT], 1);
    __syncthreads();
    if (t < nbins && hist[t] > 0)
        base[t] = bstart_e[t] + atomicAdd(&bincur[t], hist[t]);
    cur[t] = 0;
    __syncthreads();
    for (int i = c0 + t; i < iend; i += 256) {
        int s = src[i], d = dst[i];
        int b = d >> BIN_SHIFT;
        int r = atomicAdd(&cur[b], 1);
        ebuf[base[b] + r] = s | ((d & (BIN_NODES - 1)) << 17);
    }
}

// ---------------- phase 2: per-bin CSR build in LDS, coalesced write-out ----
__global__ __launch_bounds__(256) void phase2_kernel(
        const int* __restrict__ ebuf, const int* __restrict__ bstart_e,
        const int* __restrict__ row_start, int* __restrict__ csr,
        int* __restrict__ gcursor, int n, int sentinel) {
    __shared__ int image[IMG_CAP];
    __shared__ int lcur[BIN_NODES];
    int b = blockIdx.x, t = threadIdx.x;
    int n0 = b * BIN_NODES;
    int n1 = n0 + BIN_NODES; if (n1 > n) n1 = n;
    int rbase = row_start[n0];
    int rspan = row_start[n1] - rbase;
    int e0 = bstart_e[b], e1 = bstart_e[b + 1];
    for (int k = t; k < BIN_NODES; k += 256) lcur[k] = 0;
    if (rspan <= IMG_CAP) {
        for (int k = t; k < rspan; k += 256) image[k] = sentinel;
        __syncthreads();
        for (int j = e0 + t; j < e1; j += 256) {
            int en = ebuf[j];
            int s = en & 0x1FFFF;
            int dl = en >> 17;
            int pos = row_start[n0 + dl] - rbase + atomicAdd(&lcur[dl], 1);
            image[pos] = s;
        }
        __syncthreads();
        for (int k = t; k < rspan; k += 256) csr[rbase + k] = image[k];
    } else {                                        // statistically never
        __syncthreads();
        for (int j = e0 + t; j < e1; j += 256) {
            int en = ebuf[j];
            int s = en & 0x1FFFF;
            int dl = en >> 17;
            int pos = row_start[n0 + dl] + atomicAdd(&gcursor[n0 + dl], 1);
            csr[pos] = s;                           // pads from fill_kernel
        }
    }
}

// ---------------- dense linear: hs[N,64] = dinv[r] * (in[N,K] @ w[K,64]) ----
template<int K>
__global__ __launch_bounds__(256) void lin2(const float* __restrict__ in,
                                            const float* __restrict__ w,
                                            const float* __restrict__ dinv,
                                            unsigned short* __restrict__ outbf, int n) {
    constexpr int XSS = K + 4;
    __shared__ float xs[64 * XSS];
    __shared__ float ws[K * 64];
    int t = threadIdx.x;
    int row0 = blockIdx.x * 64;
    int nrows = n - row0; if (nrows > 64) nrows = 64;

    {
        const float4* w4 = (const float4*)w;
        float4* ws4 = (float4*)ws;
#pragma unroll
        for (int idx = t; idx < K * 16; idx += 256) ws4[idx] = w4[idx];
    }
    {
        const float4* in4 = (const float4*)(in + (size_t)row0 * K);
        int total4 = nrows * (K / 4);
        for (int idx = t; idx < total4; idx += 256) {
            int r = idx / (K / 4), kk = idx - r * (K / 4);
            float4 v = in4[idx];
            *(float4*)&xs[r * XSS + kk * 4] = v;
        }
    }
    __syncthreads();

    int cg = t & 15;
    int rg = t >> 4;
    float acc[4][4];
#pragma unroll
    for (int r = 0; r < 4; r++)
#pragma unroll
        for (int c = 0; c < 4; c++) acc[r][c] = 0.f;

    const float* xbase = &xs[rg * 4 * XSS];
    const float* wbase = &ws[cg * 4];
#pragma unroll 4
    for (int k = 0; k < K; k += 4) {
        float4 a0 = *(const float4*)&xbase[0 * XSS + k];
        float4 a1 = *(const float4*)&xbase[1 * XSS + k];
        float4 a2 = *(const float4*)&xbase[2 * XSS + k];
        float4 a3 = *(const float4*)&xbase[3 * XSS + k];
        float4 w0 = *(const float4*)&wbase[(k + 0) * 64];
        float4 w1 = *(const float4*)&wbase[(k + 1) * 64];
        float4 w2 = *(const float4*)&wbase[(k + 2) * 64];
        float4 w3 = *(const float4*)&wbase[(k + 3) * 64];
#pragma unroll
        for (int r = 0; r < 4; r++) {
            float4 a = (r == 0) ? a0 : (r == 1) ? a1 : (r == 2) ? a2 : a3;
            acc[r][0] += a.x * w0.x + a.y * w1.x + a.z * w2.x + a.w * w3.x;
            acc[r][1] += a.x * w0.y + a.y * w1.y + a.z * w2.y + a.w * w3.y;
            acc[r][2] += a.x * w0.z + a.y * w1.z + a.z * w2.z + a.w * w3.z;
            acc[r][3] += a.x * w0.w + a.y * w1.w + a.z * w2.w + a.w * w3.w;
        }
    }
#pragma unroll
    for (int r = 0; r < 4; r++) {
        int row = rg * 4 + r;
        if (row < nrows) {
            float dv = dinv[row0 + row];
            ushort4 v;
            v.x = f2bf(acc[r][0] * dv); v.y = f2bf(acc[r][1] * dv);
            v.z = f2bf(acc[r][2] * dv); v.w = f2bf(acc[r][3] * dv);
            *(ushort4*)&outbf[(size_t)(row0 + row) * 64 + cg * 4] = v;
        }
    }
}

// ---------------- aggregation + bias + BN + ReLU ----------------
__global__ __launch_bounds__(256) void agg_kernel(
        const unsigned short* __restrict__ hs, const int* __restrict__ row_start,
        const int* __restrict__ csr, const float* __restrict__ dinv,
        const float* __restrict__ bias, const float* __restrict__ gam,
        const float* __restrict__ bet, const float* __restrict__ mu,
        const float* __restrict__ var,
        float* __restrict__ out, int n) {
    int i = blockIdx.x * 4 + (threadIdx.x >> 6);
    int lane = threadIdx.x & 63;
    if (i >= n) return;
    float acc = bf2f(hs[(size_t)i * 64 + lane]);   // self-loop term (pre-scaled)
    int rs = row_start[i], re = row_start[i + 1];  // multiples of 8
    for (int j = rs; j < re; j += 8) {
        int4 c0 = *(const int4*)&csr[j];
        int4 c1 = *(const int4*)&csr[j + 4];
        float h0 = bf2f(hs[(size_t)c0.x * 64 + lane]);
        float h1 = bf2f(hs[(size_t)c0.y * 64 + lane]);
        float h2 = bf2f(hs[(size_t)c0.z * 64 + lane]);
        float h3 = bf2f(hs[(size_t)c0.w * 64 + lane]);
        float h4 = bf2f(hs[(size_t)c1.x * 64 + lane]);
        float h5 = bf2f(hs[(size_t)c1.y * 64 + lane]);
        float h6 = bf2f(hs[(size_t)c1.z * 64 + lane]);
        float h7 = bf2f(hs[(size_t)c1.w * 64 + lane]);
        acc += ((h0 + h1) + (h2 + h3)) + ((h4 + h5) + (h6 + h7));
    }
    float agg = acc * dinv[i];
    float scale = gam[lane] * rsqrtf(var[lane] + BN_EPS);
    float r = (agg + bias[lane] - mu[lane]) * scale + bet[lane];
    out[(size_t)i * 64 + lane] = r > 0.f ? r : 0.f;
}

// ---------------- pool stage 1: node-parallel segmented sum ----------------
#define POOL_CHUNK 64
__global__ __launch_bounds__(256) void pool_kernel(const float* __restrict__ h,
                                                   const int* __restrict__ batch,
                                                   float* __restrict__ pooled, int n) {
    int wid = blockIdx.x * 4 + (threadIdx.x >> 6);
    int lane = threadIdx.x & 63;
    int start = wid * POOL_CHUNK;
    if (start >= n) return;
    int end = start + POOL_CHUNK; if (end > n) end = n;
    int cur = batch[start];
    float acc = 0.f;
    for (int i = start; i < end; i++) {
        int b = batch[i];
        if (b != cur) {
            atomicAdd(&pooled[(size_t)cur * 64 + lane], acc);
            acc = 0.f; cur = b;
        }
        acc += h[(size_t)i * 64 + lane];
    }
    atomicAdd(&pooled[(size_t)cur * 64 + lane], acc);
}

// ---------------- pool stage 2: tiny MLP per graph ----------------
__global__ void mlp_kernel(const float* __restrict__ pooled,
                           const float* __restrict__ l1w, const float* __restrict__ l1b,
                           const float* __restrict__ l2w, const float* __restrict__ l2b,
                           float* __restrict__ out) {
    int g = blockIdx.x;
    int lane = threadIdx.x;
    __shared__ float p[64];
    __shared__ float h1[32];
    p[lane] = pooled[(size_t)g * 64 + lane];
    __syncthreads();
    if (lane < 32) {
        float a = l1b[lane];
#pragma unroll 8
        for (int k = 0; k < 64; k++) a += p[k] * l1w[k * 32 + lane];
        h1[lane] = a > 0.f ? a : 0.f;
    }
    __syncthreads();
    if (lane < 2) {
        float a = l2b[lane];
#pragma unroll 8
        for (int j = 0; j < 32; j++) a += h1[j] * l2w[j * 2 + lane];
        out[g * 2 + lane] = a;
    }
}

extern "C" void kernel_launch(void* const* d_in, const int* in_sizes, int n_in,
                              void* d_out, int out_size, void* d_ws, size_t ws_size,
                              hipStream_t stream) {
    const float* x     = (const float*)d_in[0];
    const int*   ei    = (const int*)d_in[1];
    const int*   batch = (const int*)d_in[2];
    const float* w0 = (const float*)d_in[3];
    const float* b0 = (const float*)d_in[4];
    const float* w1 = (const float*)d_in[5];
    const float* b1 = (const float*)d_in[6];
    const float* w2 = (const float*)d_in[7];
    const float* b2 = (const float*)d_in[8];
    const float* g0 = (const float*)d_in[9];
    const float* be0 = (const float*)d_in[10];
    const float* m0 = (const float*)d_in[11];
    const float* v0 = (const float*)d_in[12];
    const float* g1 = (const float*)d_in[13];
    const float* be1 = (const float*)d_in[14];
    const float* m1 = (const float*)d_in[15];
    const float* v1 = (const float*)d_in[16];
    const float* g2 = (const float*)d_in[17];
    const float* be2 = (const float*)d_in[18];
    const float* m2 = (const float*)d_in[19];
    const float* v2 = (const float*)d_in[20];
    const float* l1w = (const float*)d_in[21];
    const float* l1b = (const float*)d_in[22];
    const float* l2w = (const float*)d_in[23];
    const float* l2b = (const float*)d_in[24];
    float* out = (float*)d_out;

    const int N = in_sizes[2];
    const int E = in_sizes[1] / 2;
    const int G = out_size / 2;
    const int NBINS = (N + BIN_NODES - 1) / BIN_NODES;

    const int* src = ei;
    const int* dst = ei + E;

    // workspace layout
    char* p = (char*)d_ws;
    auto alloc = [&](size_t bytes) -> void* {
        void* r = (void*)p;
        p += (bytes + 255) & ~(size_t)255;
        return r;
    };
    const size_t CSR_CAP = ((size_t)E + 8 * (size_t)N + 3) & ~(size_t)3;
    float* dinvp    = (float*)alloc((size_t)N * 4);
    int*   cnt      = (int*)alloc((size_t)N * 4);
    int*   row_start= (int*)alloc((size_t)(N + 1) * 4);
    int*   cursor   = (int*)alloc((size_t)N * 4);
    int    NB       = (N + SCAN_CHUNK - 1) / SCAN_CHUNK;
    int*   bsums    = (int*)alloc((size_t)NB * 4);
    int*   bincnt   = (int*)alloc((size_t)NBINS * 4);
    int*   bstart_e = (int*)alloc((size_t)(NBINS + 1) * 4);
    int*   bincur   = (int*)alloc((size_t)NBINS * 4);
    int*   ebuf     = (int*)alloc((size_t)E * 4);
    int*   csr      = (int*)alloc(CSR_CAP * 4);
    unsigned short* h_a = (unsigned short*)alloc((size_t)(N + 1) * 64 * 2); // +sentinel row
    float* h_b      = (float*)alloc((size_t)N * 64 * 4);
    float* pooled   = (float*)alloc((size_t)G * 64 * 4);
    (void)ws_size;

    // ---- graph preprocessing ----
    hipMemsetAsync(cnt, 0, (size_t)N * 4, stream);
    hipMemsetAsync(cursor, 0, (size_t)N * 4, stream);
    hipMemsetAsync(bincur, 0, (size_t)NBINS * 4, stream);
    hipMemsetAsync(pooled, 0, (size_t)G * 64 * 4, stream);
    hipMemsetAsync(h_a + (size_t)N * 64, 0, 64 * 2, stream);   // zero sentinel row
    hist_kernel<<<(E + 255) / 256, 256, 0, stream>>>(dst, cnt, E);
    dinv_kernel<<<(N + 255) / 256, 256, 0, stream>>>(cnt, dinvp, N);
    scan_block_sums<<<NB, 256, 0, stream>>>(cnt, bsums, N);
    scan_exclusive_bsums<<<1, 64, 0, stream>>>(bsums, NB);
    scan_write<<<NB, 256, 0, stream>>>(cnt, bsums, row_start, N);
    binsum_kernel<<<(NBINS + 3) / 4, 256, 0, stream>>>(cnt, bincnt, N, NBINS);
    scan_small<<<1, 64, 0, stream>>>(bincnt, bstart_e, NBINS);
    {   // fill csr with sentinel N (pads + fallback safety)
        int m4 = (int)(CSR_CAP / 4);
        fill_kernel<<<(m4 + 255) / 256, 256, 0, stream>>>(csr, N, m4);
    }
    phase1_kernel<<<(E + P1_CHUNK - 1) / P1_CHUNK, 256, 0, stream>>>(
        src, dst, bstart_e, bincur, ebuf, E, NBINS);
    phase2_kernel<<<NBINS, 256, 0, stream>>>(ebuf, bstart_e, row_start, csr,
                                             cursor, N, N);

    const int nblk = (N + 3) / 4;
    const int lblk = (N + 63) / 64;
    // ---- layer 0 ----
    lin2<128><<<lblk, 256, 0, stream>>>(x, w0, dinvp, h_a, N);
    agg_kernel<<<nblk, 256, 0, stream>>>(h_a, row_start, csr, dinvp,
                                         b0, g0, be0, m0, v0, h_b, N);
    // ---- layer 1 ----
    lin2<64><<<lblk, 256, 0, stream>>>(h_b, w1, dinvp, h_a, N);
    agg_kernel<<<nblk, 256, 0, stream>>>(h_a, row_start, csr, dinvp,
                                         b1, g1, be1, m1, v1, h_b, N);
    // ---- layer 2 ----
    lin2<64><<<lblk, 256, 0, stream>>>(h_b, w2, dinvp, h_a, N);
    agg_kernel<<<nblk, 256, 0, stream>>>(h_a, row_start, csr, dinvp,
                                         b2, g2, be2, m2, v2, h_b, N);
    // ---- pool + MLP ----
    const int pwaves = (N + POOL_CHUNK - 1) / POOL_CHUNK;
    pool_kernel<<<(pwaves + 3) / 4, 256, 0, stream>>>(h_b, batch, pooled, N);
    mlp_kernel<<<G, 64, 0, stream>>>(pooled, l1w, l1b, l2w, l2b, out);
}

// Round 9
// 459.487 us; speedup vs baseline: 5.1623x; 1.1303x over previous
//
#include <hip/hip_runtime.h>
#include <hip/hip_bf16.h>

#define BN_EPS 1e-5f

static __device__ __forceinline__ unsigned short f2bf(float f) {
    unsigned u = __float_as_uint(f);
    unsigned r = (u + 0x7FFF + ((u >> 16) & 1)) >> 16;
    return (unsigned short)r;
}
static __device__ __forceinline__ float bf2f(unsigned short s) {
    return __uint_as_float((unsigned)s << 16);
}
__device__ __forceinline__ int pad8i(int c) { return (c + 7) & ~7; }

#define BIN_SHIFT 9
#define BIN_NODES 512
#define P1_CHUNK 8192
#define IMG_CAP 12288

// ---------------- exclusive scan over PADDED counts (3-pass, chunk = 1024) ----
#define SCAN_CHUNK 1024

__global__ void scan_block_sums(const int* __restrict__ cnt, int* __restrict__ bsums, int n) {
    __shared__ int sdata[256];
    int b = blockIdx.x, t = threadIdx.x;
    int base = b * SCAN_CHUNK;
    int s = 0;
    for (int i = t; i < SCAN_CHUNK; i += 256) {
        int idx = base + i;
        if (idx < n) s += pad8i(cnt[idx]);
    }
    sdata[t] = s;
    __syncthreads();
    for (int off = 128; off > 0; off >>= 1) {
        if (t < off) sdata[t] += sdata[t + off];
        __syncthreads();
    }
    if (t == 0) bsums[b] = sdata[0];
}

__global__ void scan_exclusive_bsums(int* __restrict__ bsums, int nb) {
    if (threadIdx.x == 0 && blockIdx.x == 0) {
        int acc = 0;
        for (int i = 0; i < nb; i++) { int v = bsums[i]; bsums[i] = acc; acc += v; }
    }
}

__global__ void scan_write(const int* __restrict__ cnt, const int* __restrict__ bsums,
                           int* __restrict__ row_start, int n) {
    __shared__ int sdata[256];
    int b = blockIdx.x, t = threadIdx.x;
    int base = b * SCAN_CHUNK + t * 4;
    int v0 = 0, v1 = 0, v2 = 0, v3 = 0;
    if (base + 0 < n) v0 = pad8i(cnt[base + 0]);
    if (base + 1 < n) v1 = pad8i(cnt[base + 1]);
    if (base + 2 < n) v2 = pad8i(cnt[base + 2]);
    if (base + 3 < n) v3 = pad8i(cnt[base + 3]);
    int tsum = v0 + v1 + v2 + v3;
    sdata[t] = tsum;
    __syncthreads();
    for (int off = 1; off < 256; off <<= 1) {       // inclusive Hillis-Steele
        int x = (t >= off) ? sdata[t - off] : 0;
        __syncthreads();
        sdata[t] += x;
        __syncthreads();
    }
    int excl = sdata[t] - tsum + bsums[b];
    if (base + 0 < n) row_start[base + 0] = excl;
    if (base + 1 < n) row_start[base + 1] = excl + v0;
    if (base + 2 < n) row_start[base + 2] = excl + v0 + v1;
    if (base + 3 < n) row_start[base + 3] = excl + v0 + v1 + v2;
    if (n - 1 >= base && n - 1 < base + 4)          // finalize total (padded end)
        row_start[n] = excl + v0 + v1 + v2 + v3;
}

// ---------------- bin-level histogram: LDS hist -> few global atomics -------
__global__ __launch_bounds__(256) void binhist_kernel(const int* __restrict__ dst,
                                                      int* __restrict__ bincnt,
                                                      int e, int nbins) {
    __shared__ int hist[256];
    int t = threadIdx.x;
    hist[t] = 0;
    __syncthreads();
    int c0 = blockIdx.x * P1_CHUNK;
    int iend = c0 + P1_CHUNK; if (iend > e) iend = e;
    for (int i = c0 + t; i < iend; i += 256)
        atomicAdd(&hist[dst[i] >> BIN_SHIFT], 1);
    __syncthreads();
    if (t < nbins && hist[t] > 0) atomicAdd(&bincnt[t], hist[t]);
}

__global__ void scan_small(const int* __restrict__ in, int* __restrict__ out, int m) {
    if (threadIdx.x == 0 && blockIdx.x == 0) {
        int a = 0;
        for (int i = 0; i < m; i++) { out[i] = a; a += in[i]; }
        out[m] = a;
    }
}

// ---------------- phase 1: partition edges into 512-node bins --------------
__global__ __launch_bounds__(256) void phase1_kernel(
        const int* __restrict__ src, const int* __restrict__ dst,
        const int* __restrict__ bstart_e, int* __restrict__ bincur,
        int* __restrict__ ebuf, int e, int nbins) {
    __shared__ int hist[256], base[256], cur[256];
    int t = threadIdx.x;
    int c0 = blockIdx.x * P1_CHUNK;
    int iend = c0 + P1_CHUNK; if (iend > e) iend = e;
    hist[t] = 0;
    __syncthreads();
    for (int i = c0 + t; i < iend; i += 256)
        atomicAdd(&hist[dst[i] >> BIN_SHIFT], 1);
    __syncthreads();
    if (t < nbins && hist[t] > 0)
        base[t] = bstart_e[t] + atomicAdd(&bincur[t], hist[t]);
    cur[t] = 0;
    __syncthreads();
    for (int i = c0 + t; i < iend; i += 256) {
        int s = src[i], d = dst[i];
        int b = d >> BIN_SHIFT;
        int r = atomicAdd(&cur[b], 1);
        ebuf[base[b] + r] = s | ((d & (BIN_NODES - 1)) << 17);
    }
}

// ---------------- per-node counts + dinv from binned edges (LDS only) ------
__global__ __launch_bounds__(256) void bincount_kernel(
        const int* __restrict__ ebuf, const int* __restrict__ bstart_e,
        int* __restrict__ cnt, float* __restrict__ dinv, int n) {
    __shared__ int c512[BIN_NODES];
    int b = blockIdx.x, t = threadIdx.x;
    for (int k = t; k < BIN_NODES; k += 256) c512[k] = 0;
    __syncthreads();
    int e0 = bstart_e[b], e1 = bstart_e[b + 1];
    for (int j = e0 + t; j < e1; j += 256)
        atomicAdd(&c512[ebuf[j] >> 17], 1);
    __syncthreads();
    int n0 = b * BIN_NODES;
    for (int k = t; k < BIN_NODES; k += 256) {
        int i = n0 + k;
        if (i < n) {
            int c = c512[k];
            cnt[i] = c;
            dinv[i] = rsqrtf((float)(c + 1));
        }
    }
}

// ---------------- phase 2: per-bin CSR build in LDS, coalesced write-out ----
__global__ __launch_bounds__(256) void phase2_kernel(
        const int* __restrict__ ebuf, const int* __restrict__ bstart_e,
        const int* __restrict__ row_start, int* __restrict__ csr,
        int* __restrict__ gcursor, int n, int sentinel) {
    __shared__ int image[IMG_CAP];
    __shared__ int lcur[BIN_NODES];
    int b = blockIdx.x, t = threadIdx.x;
    int n0 = b * BIN_NODES;
    int n1 = n0 + BIN_NODES; if (n1 > n) n1 = n;
    int rbase = row_start[n0];
    int rspan = row_start[n1] - rbase;
    int e0 = bstart_e[b], e1 = bstart_e[b + 1];
    for (int k = t; k < BIN_NODES; k += 256) lcur[k] = 0;
    if (rspan <= IMG_CAP) {
        for (int k = t; k < rspan; k += 256) image[k] = sentinel;
        __syncthreads();
        for (int j = e0 + t; j < e1; j += 256) {
            int en = ebuf[j];
            int s = en & 0x1FFFF;
            int dl = en >> 17;
            int pos = row_start[n0 + dl] - rbase + atomicAdd(&lcur[dl], 1);
            image[pos] = s;
        }
        __syncthreads();
        for (int k = t; k < rspan; k += 256) csr[rbase + k] = image[k];
    } else {                                        // statistically never
        __syncthreads();
        for (int j = e0 + t; j < e1; j += 256) {
            int en = ebuf[j];
            int s = en & 0x1FFFF;
            int dl = en >> 17;
            int pos = row_start[n0 + dl] + atomicAdd(&gcursor[n0 + dl], 1);
            csr[pos] = s;
        }
        __syncthreads();
        for (int k = t; k < n1 - n0; k += 256) {    // fill pads with sentinel
            int node = n0 + k;
            int c = gcursor[node];
            for (int pos = row_start[node] + c; pos < row_start[node + 1]; pos++)
                csr[pos] = sentinel;
        }
    }
}

// ---------------- dense linear: hs[N,64] = dinv[r] * (in[N,K] @ w[K,64]) ----
// BF16IN: input rows are bf16 (layers 1,2); else fp32 (layer 0).
template<int K, bool BF16IN>
__global__ __launch_bounds__(256) void lin2(const void* __restrict__ in_,
                                            const float* __restrict__ w,
                                            const float* __restrict__ dinv,
                                            unsigned short* __restrict__ outbf, int n) {
    constexpr int XSS = K + 4;
    __shared__ float xs[64 * XSS];
    __shared__ float ws[K * 64];
    int t = threadIdx.x;
    int row0 = blockIdx.x * 64;
    int nrows = n - row0; if (nrows > 64) nrows = 64;

    {
        const float4* w4 = (const float4*)w;
        float4* ws4 = (float4*)ws;
#pragma unroll
        for (int idx = t; idx < K * 16; idx += 256) ws4[idx] = w4[idx];
    }
    if constexpr (BF16IN) {
        const uint4* in4 = (const uint4*)((const unsigned short*)in_ + (size_t)row0 * K);
        int total8 = nrows * (K / 8);
        for (int idx = t; idx < total8; idx += 256) {
            int r = idx / (K / 8), kk = idx - r * (K / 8);
            uint4 v = in4[idx];
            float* d = &xs[r * XSS + kk * 8];
            d[0] = bf2f(v.x & 0xffff); d[1] = bf2f(v.x >> 16);
            d[2] = bf2f(v.y & 0xffff); d[3] = bf2f(v.y >> 16);
            d[4] = bf2f(v.z & 0xffff); d[5] = bf2f(v.z >> 16);
            d[6] = bf2f(v.w & 0xffff); d[7] = bf2f(v.w >> 16);
        }
    } else {
        const float4* in4 = (const float4*)((const float*)in_ + (size_t)row0 * K);
        int total4 = nrows * (K / 4);
        for (int idx = t; idx < total4; idx += 256) {
            int r = idx / (K / 4), kk = idx - r * (K / 4);
            float4 v = in4[idx];
            *(float4*)&xs[r * XSS + kk * 4] = v;
        }
    }
    __syncthreads();

    int cg = t & 15;
    int rg = t >> 4;
    float acc[4][4];
#pragma unroll
    for (int r = 0; r < 4; r++)
#pragma unroll
        for (int c = 0; c < 4; c++) acc[r][c] = 0.f;

    const float* xbase = &xs[rg * 4 * XSS];
    const float* wbase = &ws[cg * 4];
#pragma unroll 4
    for (int k = 0; k < K; k += 4) {
        float4 a0 = *(const float4*)&xbase[0 * XSS + k];
        float4 a1 = *(const float4*)&xbase[1 * XSS + k];
        float4 a2 = *(const float4*)&xbase[2 * XSS + k];
        float4 a3 = *(const float4*)&xbase[3 * XSS + k];
        float4 w0 = *(const float4*)&wbase[(k + 0) * 64];
        float4 w1 = *(const float4*)&wbase[(k + 1) * 64];
        float4 w2 = *(const float4*)&wbase[(k + 2) * 64];
        float4 w3 = *(const float4*)&wbase[(k + 3) * 64];
#pragma unroll
        for (int r = 0; r < 4; r++) {
            float4 a = (r == 0) ? a0 : (r == 1) ? a1 : (r == 2) ? a2 : a3;
            acc[r][0] += a.x * w0.x + a.y * w1.x + a.z * w2.x + a.w * w3.x;
            acc[r][1] += a.x * w0.y + a.y * w1.y + a.z * w2.y + a.w * w3.y;
            acc[r][2] += a.x * w0.z + a.y * w1.z + a.z * w2.z + a.w * w3.z;
            acc[r][3] += a.x * w0.w + a.y * w1.w + a.z * w2.w + a.w * w3.w;
        }
    }
#pragma unroll
    for (int r = 0; r < 4; r++) {
        int row = rg * 4 + r;
        if (row < nrows) {
            float dv = dinv[row0 + row];
            ushort4 v;
            v.x = f2bf(acc[r][0] * dv); v.y = f2bf(acc[r][1] * dv);
            v.z = f2bf(acc[r][2] * dv); v.w = f2bf(acc[r][3] * dv);
            *(ushort4*)&outbf[(size_t)(row0 + row) * 64 + cg * 4] = v;
        }
    }
}

// ---------------- aggregation + bias + BN + ReLU (bf16 out) ----------------
__global__ __launch_bounds__(256) void agg_kernel(
        const unsigned short* __restrict__ hs, const int* __restrict__ row_start,
        const int* __restrict__ csr, const float* __restrict__ dinv,
        const float* __restrict__ bias, const float* __restrict__ gam,
        const float* __restrict__ bet, const float* __restrict__ mu,
        const float* __restrict__ var,
        unsigned short* __restrict__ out, int n) {
    int i = blockIdx.x * 4 + (threadIdx.x >> 6);
    int lane = threadIdx.x & 63;
    if (i >= n) return;
    float acc = bf2f(hs[(size_t)i * 64 + lane]);   // self-loop term (pre-scaled)
    int rs = row_start[i], re = row_start[i + 1];  // multiples of 8
    for (int j = rs; j < re; j += 8) {
        int4 c0 = *(const int4*)&csr[j];
        int4 c1 = *(const int4*)&csr[j + 4];
        float h0 = bf2f(hs[(size_t)c0.x * 64 + lane]);
        float h1 = bf2f(hs[(size_t)c0.y * 64 + lane]);
        float h2 = bf2f(hs[(size_t)c0.z * 64 + lane]);
        float h3 = bf2f(hs[(size_t)c0.w * 64 + lane]);
        float h4 = bf2f(hs[(size_t)c1.x * 64 + lane]);
        float h5 = bf2f(hs[(size_t)c1.y * 64 + lane]);
        float h6 = bf2f(hs[(size_t)c1.z * 64 + lane]);
        float h7 = bf2f(hs[(size_t)c1.w * 64 + lane]);
        acc += ((h0 + h1) + (h2 + h3)) + ((h4 + h5) + (h6 + h7));
    }
    float agg = acc * dinv[i];
    float scale = gam[lane] * rsqrtf(var[lane] + BN_EPS);
    float r = (agg + bias[lane] - mu[lane]) * scale + bet[lane];
    out[(size_t)i * 64 + lane] = f2bf(r > 0.f ? r : 0.f);
}

// ---------------- pool stage 1: node-parallel segmented sum (bf16 in) ------
#define POOL_CHUNK 64
__global__ __launch_bounds__(256) void pool_kernel(const unsigned short* __restrict__ h,
                                                   const int* __restrict__ batch,
                                                   float* __restrict__ pooled, int n) {
    int wid = blockIdx.x * 4 + (threadIdx.x >> 6);
    int lane = threadIdx.x & 63;
    int start = wid * POOL_CHUNK;
    if (start >= n) return;
    int end = start + POOL_CHUNK; if (end > n) end = n;
    int cur = batch[start];
    float acc = 0.f;
    for (int i = start; i < end; i++) {
        int b = batch[i];
        if (b != cur) {
            atomicAdd(&pooled[(size_t)cur * 64 + lane], acc);
            acc = 0.f; cur = b;
        }
        acc += bf2f(h[(size_t)i * 64 + lane]);
    }
    atomicAdd(&pooled[(size_t)cur * 64 + lane], acc);
}

// ---------------- pool stage 2: tiny MLP per graph ----------------
__global__ void mlp_kernel(const float* __restrict__ pooled,
                           const float* __restrict__ l1w, const float* __restrict__ l1b,
                           const float* __restrict__ l2w, const float* __restrict__ l2b,
                           float* __restrict__ out) {
    int g = blockIdx.x;
    int lane = threadIdx.x;
    __shared__ float p[64];
    __shared__ float h1[32];
    p[lane] = pooled[(size_t)g * 64 + lane];
    __syncthreads();
    if (lane < 32) {
        float a = l1b[lane];
#pragma unroll 8
        for (int k = 0; k < 64; k++) a += p[k] * l1w[k * 32 + lane];
        h1[lane] = a > 0.f ? a : 0.f;
    }
    __syncthreads();
    if (lane < 2) {
        float a = l2b[lane];
#pragma unroll 8
        for (int j = 0; j < 32; j++) a += h1[j] * l2w[j * 2 + lane];
        out[g * 2 + lane] = a;
    }
}

extern "C" void kernel_launch(void* const* d_in, const int* in_sizes, int n_in,
                              void* d_out, int out_size, void* d_ws, size_t ws_size,
                              hipStream_t stream) {
    const float* x     = (const float*)d_in[0];
    const int*   ei    = (const int*)d_in[1];
    const int*   batch = (const int*)d_in[2];
    const float* w0 = (const float*)d_in[3];
    const float* b0 = (const float*)d_in[4];
    const float* w1 = (const float*)d_in[5];
    const float* b1 = (const float*)d_in[6];
    const float* w2 = (const float*)d_in[7];
    const float* b2 = (const float*)d_in[8];
    const float* g0 = (const float*)d_in[9];
    const float* be0 = (const float*)d_in[10];
    const float* m0 = (const float*)d_in[11];
    const float* v0 = (const float*)d_in[12];
    const float* g1 = (const float*)d_in[13];
    const float* be1 = (const float*)d_in[14];
    const float* m1 = (const float*)d_in[15];
    const float* v1 = (const float*)d_in[16];
    const float* g2 = (const float*)d_in[17];
    const float* be2 = (const float*)d_in[18];
    const float* m2 = (const float*)d_in[19];
    const float* v2 = (const float*)d_in[20];
    const float* l1w = (const float*)d_in[21];
    const float* l1b = (const float*)d_in[22];
    const float* l2w = (const float*)d_in[23];
    const float* l2b = (const float*)d_in[24];
    float* out = (float*)d_out;

    const int N = in_sizes[2];
    const int E = in_sizes[1] / 2;
    const int G = out_size / 2;
    const int NBINS = (N + BIN_NODES - 1) / BIN_NODES;

    const int* src = ei;
    const int* dst = ei + E;

    // workspace layout
    char* p = (char*)d_ws;
    auto alloc = [&](size_t bytes) -> void* {
        void* r = (void*)p;
        p += (bytes + 255) & ~(size_t)255;
        return r;
    };
    const size_t CSR_CAP = ((size_t)E + 8 * (size_t)N + 3) & ~(size_t)3;
    float* dinvp    = (float*)alloc((size_t)N * 4);
    int*   cnt      = (int*)alloc((size_t)N * 4);
    int*   row_start= (int*)alloc((size_t)(N + 1) * 4);
    int*   cursor   = (int*)alloc((size_t)N * 4);
    int    NB       = (N + SCAN_CHUNK - 1) / SCAN_CHUNK;
    int*   bsums    = (int*)alloc((size_t)NB * 4);
    int*   bincnt   = (int*)alloc((size_t)NBINS * 4);
    int*   bstart_e = (int*)alloc((size_t)(NBINS + 1) * 4);
    int*   bincur   = (int*)alloc((size_t)NBINS * 4);
    int*   ebuf     = (int*)alloc((size_t)E * 4);
    int*   csr      = (int*)alloc(CSR_CAP * 4);
    unsigned short* h_a = (unsigned short*)alloc((size_t)(N + 1) * 64 * 2); // +sentinel row
    unsigned short* h_b = (unsigned short*)alloc((size_t)N * 64 * 2);       // bf16 agg out
    float* pooled   = (float*)alloc((size_t)G * 64 * 4);
    (void)ws_size;

    // ---- graph preprocessing ----
    hipMemsetAsync(cursor, 0, (size_t)N * 4, stream);
    hipMemsetAsync(bincnt, 0, (size_t)NBINS * 4, stream);
    hipMemsetAsync(bincur, 0, (size_t)NBINS * 4, stream);
    hipMemsetAsync(pooled, 0, (size_t)G * 64 * 4, stream);
    hipMemsetAsync(h_a + (size_t)N * 64, 0, 64 * 2, stream);   // zero sentinel row
    const int nchunks = (E + P1_CHUNK - 1) / P1_CHUNK;
    binhist_kernel<<<nchunks, 256, 0, stream>>>(dst, bincnt, E, NBINS);
    scan_small<<<1, 64, 0, stream>>>(bincnt, bstart_e, NBINS);
    phase1_kernel<<<nchunks, 256, 0, stream>>>(src, dst, bstart_e, bincur, ebuf, E, NBINS);
    bincount_kernel<<<NBINS, 256, 0, stream>>>(ebuf, bstart_e, cnt, dinvp, N);
    scan_block_sums<<<NB, 256, 0, stream>>>(cnt, bsums, N);
    scan_exclusive_bsums<<<1, 64, 0, stream>>>(bsums, NB);
    scan_write<<<NB, 256, 0, stream>>>(cnt, bsums, row_start, N);
    phase2_kernel<<<NBINS, 256, 0, stream>>>(ebuf, bstart_e, row_start, csr,
                                             cursor, N, N);

    const int nblk = (N + 3) / 4;
    const int lblk = (N + 63) / 64;
    // ---- layer 0 ----
    lin2<128, false><<<lblk, 256, 0, stream>>>(x, w0, dinvp, h_a, N);
    agg_kernel<<<nblk, 256, 0, stream>>>(h_a, row_start, csr, dinvp,
                                         b0, g0, be0, m0, v0, h_b, N);
    // ---- layer 1 ----
    lin2<64, true><<<lblk, 256, 0, stream>>>(h_b, w1, dinvp, h_a, N);
    agg_kernel<<<nblk, 256, 0, stream>>>(h_a, row_start, csr, dinvp,
                                         b1, g1, be1, m1, v1, h_b, N);
    // ---- layer 2 ----
    lin2<64, true><<<lblk, 256, 0, stream>>>(h_b, w2, dinvp, h_a, N);
    agg_kernel<<<nblk, 256, 0, stream>>>(h_a, row_start, csr, dinvp,
                                         b2, g2, be2, m2, v2, h_b, N);
    // ---- pool + MLP ----
    const int pwaves = (N + POOL_CHUNK - 1) / POOL_CHUNK;
    pool_kernel<<<(pwaves + 3) / 4, 256, 0, stream>>>(h_b, batch, pooled, N);
    mlp_kernel<<<G, 64, 0, stream>>>(pooled, l1w, l1b, l2w, l2b, out);
}

// Round 10
// 431.147 us; speedup vs baseline: 5.5016x; 1.0657x over previous
//
#include <hip/hip_runtime.h>
#include <hip/hip_bf16.h>

#define BN_EPS 1e-5f

typedef short bf16x8 __attribute__((ext_vector_type(8)));
typedef float f32x4 __attribute__((ext_vector_type(4)));

static __device__ __forceinline__ unsigned short f2bf(float f) {
    unsigned u = __float_as_uint(f);
    unsigned r = (u + 0x7FFF + ((u >> 16) & 1)) >> 16;
    return (unsigned short)r;
}
static __device__ __forceinline__ float bf2f(unsigned short s) {
    return __uint_as_float((unsigned)s << 16);
}
__device__ __forceinline__ int pad8i(int c) { return (c + 7) & ~7; }

#define BIN_SHIFT 9
#define BIN_NODES 512
#define P1_CHUNK 8192
#define IMG_CAP 12288

// ---------------- exclusive scan over PADDED counts (3-pass, chunk = 1024) ----
#define SCAN_CHUNK 1024

__global__ void scan_block_sums(const int* __restrict__ cnt, int* __restrict__ bsums, int n) {
    __shared__ int sdata[256];
    int b = blockIdx.x, t = threadIdx.x;
    int base = b * SCAN_CHUNK;
    int s = 0;
    for (int i = t; i < SCAN_CHUNK; i += 256) {
        int idx = base + i;
        if (idx < n) s += pad8i(cnt[idx]);
    }
    sdata[t] = s;
    __syncthreads();
    for (int off = 128; off > 0; off >>= 1) {
        if (t < off) sdata[t] += sdata[t + off];
        __syncthreads();
    }
    if (t == 0) bsums[b] = sdata[0];
}

__global__ void scan_exclusive_bsums(int* __restrict__ bsums, int nb) {
    if (threadIdx.x == 0 && blockIdx.x == 0) {
        int acc = 0;
        for (int i = 0; i < nb; i++) { int v = bsums[i]; bsums[i] = acc; acc += v; }
    }
}

__global__ void scan_write(const int* __restrict__ cnt, const int* __restrict__ bsums,
                           int* __restrict__ row_start, int n) {
    __shared__ int sdata[256];
    int b = blockIdx.x, t = threadIdx.x;
    int base = b * SCAN_CHUNK + t * 4;
    int v0 = 0, v1 = 0, v2 = 0, v3 = 0;
    if (base + 0 < n) v0 = pad8i(cnt[base + 0]);
    if (base + 1 < n) v1 = pad8i(cnt[base + 1]);
    if (base + 2 < n) v2 = pad8i(cnt[base + 2]);
    if (base + 3 < n) v3 = pad8i(cnt[base + 3]);
    int tsum = v0 + v1 + v2 + v3;
    sdata[t] = tsum;
    __syncthreads();
    for (int off = 1; off < 256; off <<= 1) {       // inclusive Hillis-Steele
        int x = (t >= off) ? sdata[t - off] : 0;
        __syncthreads();
        sdata[t] += x;
        __syncthreads();
    }
    int excl = sdata[t] - tsum + bsums[b];
    if (base + 0 < n) row_start[base + 0] = excl;
    if (base + 1 < n) row_start[base + 1] = excl + v0;
    if (base + 2 < n) row_start[base + 2] = excl + v0 + v1;
    if (base + 3 < n) row_start[base + 3] = excl + v0 + v1 + v2;
    if (n - 1 >= base && n - 1 < base + 4)          // finalize total (padded end)
        row_start[n] = excl + v0 + v1 + v2 + v3;
}

// ---------------- bin-level histogram: LDS hist -> few global atomics -------
__global__ __launch_bounds__(256) void binhist_kernel(const int* __restrict__ dst,
                                                      int* __restrict__ bincnt,
                                                      int e, int nbins) {
    __shared__ int hist[256];
    int t = threadIdx.x;
    hist[t] = 0;
    __syncthreads();
    int c0 = blockIdx.x * P1_CHUNK;
    int iend = c0 + P1_CHUNK; if (iend > e) iend = e;
    for (int i = c0 + t; i < iend; i += 256)
        atomicAdd(&hist[dst[i] >> BIN_SHIFT], 1);
    __syncthreads();
    if (t < nbins && hist[t] > 0) atomicAdd(&bincnt[t], hist[t]);
}

__global__ void scan_small(const int* __restrict__ in, int* __restrict__ out, int m) {
    if (threadIdx.x == 0 && blockIdx.x == 0) {
        int a = 0;
        for (int i = 0; i < m; i++) { out[i] = a; a += in[i]; }
        out[m] = a;
    }
}

// ---------------- phase 1: partition edges into 512-node bins --------------
__global__ __launch_bounds__(256) void phase1_kernel(
        const int* __restrict__ src, const int* __restrict__ dst,
        const int* __restrict__ bstart_e, int* __restrict__ bincur,
        int* __restrict__ ebuf, int e, int nbins) {
    __shared__ int hist[256], base[256], cur[256];
    int t = threadIdx.x;
    int c0 = blockIdx.x * P1_CHUNK;
    int iend = c0 + P1_CHUNK; if (iend > e) iend = e;
    hist[t] = 0;
    __syncthreads();
    for (int i = c0 + t; i < iend; i += 256)
        atomicAdd(&hist[dst[i] >> BIN_SHIFT], 1);
    __syncthreads();
    if (t < nbins && hist[t] > 0)
        base[t] = bstart_e[t] + atomicAdd(&bincur[t], hist[t]);
    cur[t] = 0;
    __syncthreads();
    for (int i = c0 + t; i < iend; i += 256) {
        int s = src[i], d = dst[i];
        int b = d >> BIN_SHIFT;
        int r = atomicAdd(&cur[b], 1);
        ebuf[base[b] + r] = s | ((d & (BIN_NODES - 1)) << 17);
    }
}

// ---------------- per-node counts + dinv from binned edges (LDS only) ------
__global__ __launch_bounds__(256) void bincount_kernel(
        const int* __restrict__ ebuf, const int* __restrict__ bstart_e,
        int* __restrict__ cnt, float* __restrict__ dinv, int n) {
    __shared__ int c512[BIN_NODES];
    int b = blockIdx.x, t = threadIdx.x;
    for (int k = t; k < BIN_NODES; k += 256) c512[k] = 0;
    __syncthreads();
    int e0 = bstart_e[b], e1 = bstart_e[b + 1];
    for (int j = e0 + t; j < e1; j += 256)
        atomicAdd(&c512[ebuf[j] >> 17], 1);
    __syncthreads();
    int n0 = b * BIN_NODES;
    for (int k = t; k < BIN_NODES; k += 256) {
        int i = n0 + k;
        if (i < n) {
            int c = c512[k];
            cnt[i] = c;
            dinv[i] = rsqrtf((float)(c + 1));
        }
    }
}

// ---------------- phase 2: per-bin CSR build in LDS, coalesced write-out ----
__global__ __launch_bounds__(256) void phase2_kernel(
        const int* __restrict__ ebuf, const int* __restrict__ bstart_e,
        const int* __restrict__ row_start, int* __restrict__ csr,
        int* __restrict__ gcursor, int n, int sentinel) {
    __shared__ int image[IMG_CAP];
    __shared__ int lcur[BIN_NODES];
    int b = blockIdx.x, t = threadIdx.x;
    int n0 = b * BIN_NODES;
    int n1 = n0 + BIN_NODES; if (n1 > n) n1 = n;
    int rbase = row_start[n0];
    int rspan = row_start[n1] - rbase;
    int e0 = bstart_e[b], e1 = bstart_e[b + 1];
    for (int k = t; k < BIN_NODES; k += 256) lcur[k] = 0;
    if (rspan <= IMG_CAP) {
        for (int k = t; k < rspan; k += 256) image[k] = sentinel;
        __syncthreads();
        for (int j = e0 + t; j < e1; j += 256) {
            int en = ebuf[j];
            int s = en & 0x1FFFF;
            int dl = en >> 17;
            int pos = row_start[n0 + dl] - rbase + atomicAdd(&lcur[dl], 1);
            image[pos] = s;
        }
        __syncthreads();
        for (int k = t; k < rspan; k += 256) csr[rbase + k] = image[k];
    } else {                                        // statistically never
        __syncthreads();
        for (int j = e0 + t; j < e1; j += 256) {
            int en = ebuf[j];
            int s = en & 0x1FFFF;
            int dl = en >> 17;
            int pos = row_start[n0 + dl] + atomicAdd(&gcursor[n0 + dl], 1);
            csr[pos] = s;
        }
        __syncthreads();
        for (int k = t; k < n1 - n0; k += 256) {    // fill pads with sentinel
            int node = n0 + k;
            int c = gcursor[node];
            for (int pos = row_start[node] + c; pos < row_start[node + 1]; pos++)
                csr[pos] = sentinel;
        }
    }
}

// ---------------- MFMA linear: hs[N,64] = dinv[r] * (in[N,K] @ w[K,64]) ----
// block = 256 thr = 4 waves; 64-row tile; xs + wT staged bf16 in LDS;
// each wave: 16 rows x 64 cols via 16x16x32 bf16 MFMA.
// Verified layouts: A: m=lane&15, k=quad*8+j (one b128); C/D: col=lane&15,
// row=quad*4+reg.
template<int K, bool BF16IN>
__global__ __launch_bounds__(256) void lin_mfma(const void* __restrict__ in_,
                                                const float* __restrict__ w,
                                                const float* __restrict__ dinv,
                                                unsigned short* __restrict__ outbf, int n) {
    constexpr int XS = K + 8;                       // shorts; keeps 16B row alignment
    __shared__ unsigned short xs[64 * XS];
    __shared__ unsigned short wt[64 * XS];          // transposed w: wt[col][k]
    int t = threadIdx.x;
    int row0 = blockIdx.x * 64;
    int nrows = n - row0; if (nrows > 64) nrows = 64;

    {   // stage w transposed (float4 reads; scattered 2B LDS writes - small)
        const float4* w4 = (const float4*)w;
        for (int idx = t; idx < K * 16; idx += 256) {
            int k = idx >> 4, c4 = (idx & 15) * 4;
            float4 v = w4[idx];
            wt[(c4 + 0) * XS + k] = f2bf(v.x);
            wt[(c4 + 1) * XS + k] = f2bf(v.y);
            wt[(c4 + 2) * XS + k] = f2bf(v.z);
            wt[(c4 + 3) * XS + k] = f2bf(v.w);
        }
    }
    if constexpr (BF16IN) {
        const uint4* in4 = (const uint4*)((const unsigned short*)in_ + (size_t)row0 * K);
        int total8 = nrows * (K / 8);
        for (int idx = t; idx < total8; idx += 256) {
            int r = idx / (K / 8), kk = idx - r * (K / 8);
            uint4 v = in4[idx];
            *(uint4*)&xs[r * XS + kk * 8] = v;      // 16B aligned
        }
    } else {
        const float4* in4 = (const float4*)((const float*)in_ + (size_t)row0 * K);
        int total4 = nrows * (K / 4);
        for (int idx = t; idx < total4; idx += 256) {
            int r = idx / (K / 4), kk = idx - r * (K / 4);
            float4 v = in4[idx];
            ushort4 s4;
            s4.x = f2bf(v.x); s4.y = f2bf(v.y); s4.z = f2bf(v.z); s4.w = f2bf(v.w);
            *(ushort4*)&xs[r * XS + kk * 4] = s4;   // 8B aligned
        }
    }
    __syncthreads();

    int lane = t & 63;
    int wid = t >> 6;
    int quad = lane >> 4;
    int l15 = lane & 15;

    f32x4 acc[4];
#pragma unroll
    for (int cg = 0; cg < 4; cg++) acc[cg] = (f32x4){0.f, 0.f, 0.f, 0.f};

    const unsigned short* arow = &xs[(wid * 16 + l15) * XS + quad * 8];
#pragma unroll
    for (int kc = 0; kc < K / 32; kc++) {
        bf16x8 a = *(const bf16x8*)(arow + kc * 32);
#pragma unroll
        for (int cg = 0; cg < 4; cg++) {
            bf16x8 b = *(const bf16x8*)&wt[(cg * 16 + l15) * XS + kc * 32 + quad * 8];
            acc[cg] = __builtin_amdgcn_mfma_f32_16x16x32_bf16(a, b, acc[cg], 0, 0, 0);
        }
    }

#pragma unroll
    for (int r = 0; r < 4; r++) {
        int grow = row0 + wid * 16 + quad * 4 + r;
        if (grow < n) {
            float dv = dinv[grow];
#pragma unroll
            for (int cg = 0; cg < 4; cg++)
                outbf[(size_t)grow * 64 + cg * 16 + l15] = f2bf(acc[cg][r] * dv);
        }
    }
}

// ---------------- aggregation + bias + BN + ReLU (bf16 out) ----------------
__global__ __launch_bounds__(256) void agg_kernel(
        const unsigned short* __restrict__ hs, const int* __restrict__ row_start,
        const int* __restrict__ csr, const float* __restrict__ dinv,
        const float* __restrict__ bias, const float* __restrict__ gam,
        const float* __restrict__ bet, const float* __restrict__ mu,
        const float* __restrict__ var,
        unsigned short* __restrict__ out, int n) {
    int i = blockIdx.x * 4 + (threadIdx.x >> 6);
    int lane = threadIdx.x & 63;
    if (i >= n) return;
    float acc = bf2f(hs[(size_t)i * 64 + lane]);   // self-loop term (pre-scaled)
    int rs = row_start[i], re = row_start[i + 1];  // multiples of 8
    for (int j = rs; j < re; j += 8) {
        int4 c0 = *(const int4*)&csr[j];
        int4 c1 = *(const int4*)&csr[j + 4];
        float h0 = bf2f(hs[(size_t)c0.x * 64 + lane]);
        float h1 = bf2f(hs[(size_t)c0.y * 64 + lane]);
        float h2 = bf2f(hs[(size_t)c0.z * 64 + lane]);
        float h3 = bf2f(hs[(size_t)c0.w * 64 + lane]);
        float h4 = bf2f(hs[(size_t)c1.x * 64 + lane]);
        float h5 = bf2f(hs[(size_t)c1.y * 64 + lane]);
        float h6 = bf2f(hs[(size_t)c1.z * 64 + lane]);
        float h7 = bf2f(hs[(size_t)c1.w * 64 + lane]);
        acc += ((h0 + h1) + (h2 + h3)) + ((h4 + h5) + (h6 + h7));
    }
    float agg = acc * dinv[i];
    float scale = gam[lane] * rsqrtf(var[lane] + BN_EPS);
    float r = (agg + bias[lane] - mu[lane]) * scale + bet[lane];
    out[(size_t)i * 64 + lane] = f2bf(r > 0.f ? r : 0.f);
}

// ---------------- pool stage 1: node-parallel segmented sum (bf16 in) ------
#define POOL_CHUNK 64
__global__ __launch_bounds__(256) void pool_kernel(const unsigned short* __restrict__ h,
                                                   const int* __restrict__ batch,
                                                   float* __restrict__ pooled, int n) {
    int wid = blockIdx.x * 4 + (threadIdx.x >> 6);
    int lane = threadIdx.x & 63;
    int start = wid * POOL_CHUNK;
    if (start >= n) return;
    int end = start + POOL_CHUNK; if (end > n) end = n;
    int cur = batch[start];
    float acc = 0.f;
    for (int i = start; i < end; i++) {
        int b = batch[i];
        if (b != cur) {
            atomicAdd(&pooled[(size_t)cur * 64 + lane], acc);
            acc = 0.f; cur = b;
        }
        acc += bf2f(h[(size_t)i * 64 + lane]);
    }
    atomicAdd(&pooled[(size_t)cur * 64 + lane], acc);
}

// ---------------- pool stage 2: tiny MLP per graph ----------------
__global__ void mlp_kernel(const float* __restrict__ pooled,
                           const float* __restrict__ l1w, const float* __restrict__ l1b,
                           const float* __restrict__ l2w, const float* __restrict__ l2b,
                           float* __restrict__ out) {
    int g = blockIdx.x;
    int lane = threadIdx.x;
    __shared__ float p[64];
    __shared__ float h1[32];
    p[lane] = pooled[(size_t)g * 64 + lane];
    __syncthreads();
    if (lane < 32) {
        float a = l1b[lane];
#pragma unroll 8
        for (int k = 0; k < 64; k++) a += p[k] * l1w[k * 32 + lane];
        h1[lane] = a > 0.f ? a : 0.f;
    }
    __syncthreads();
    if (lane < 2) {
        float a = l2b[lane];
#pragma unroll 8
        for (int j = 0; j < 32; j++) a += h1[j] * l2w[j * 2 + lane];
        out[g * 2 + lane] = a;
    }
}

extern "C" void kernel_launch(void* const* d_in, const int* in_sizes, int n_in,
                              void* d_out, int out_size, void* d_ws, size_t ws_size,
                              hipStream_t stream) {
    const float* x     = (const float*)d_in[0];
    const int*   ei    = (const int*)d_in[1];
    const int*   batch = (const int*)d_in[2];
    const float* w0 = (const float*)d_in[3];
    const float* b0 = (const float*)d_in[4];
    const float* w1 = (const float*)d_in[5];
    const float* b1 = (const float*)d_in[6];
    const float* w2 = (const float*)d_in[7];
    const float* b2 = (const float*)d_in[8];
    const float* g0 = (const float*)d_in[9];
    const float* be0 = (const float*)d_in[10];
    const float* m0 = (const float*)d_in[11];
    const float* v0 = (const float*)d_in[12];
    const float* g1 = (const float*)d_in[13];
    const float* be1 = (const float*)d_in[14];
    const float* m1 = (const float*)d_in[15];
    const float* v1 = (const float*)d_in[16];
    const float* g2 = (const float*)d_in[17];
    const float* be2 = (const float*)d_in[18];
    const float* m2 = (const float*)d_in[19];
    const float* v2 = (const float*)d_in[20];
    const float* l1w = (const float*)d_in[21];
    const float* l1b = (const float*)d_in[22];
    const float* l2w = (const float*)d_in[23];
    const float* l2b = (const float*)d_in[24];
    float* out = (float*)d_out;

    const int N = in_sizes[2];
    const int E = in_sizes[1] / 2;
    const int G = out_size / 2;
    const int NBINS = (N + BIN_NODES - 1) / BIN_NODES;

    const int* src = ei;
    const int* dst = ei + E;

    // workspace layout
    char* p = (char*)d_ws;
    auto alloc = [&](size_t bytes) -> void* {
        void* r = (void*)p;
        p += (bytes + 255) & ~(size_t)255;
        return r;
    };
    const size_t CSR_CAP = ((size_t)E + 8 * (size_t)N + 3) & ~(size_t)3;
    float* dinvp    = (float*)alloc((size_t)N * 4);
    int*   cnt      = (int*)alloc((size_t)N * 4);
    int*   row_start= (int*)alloc((size_t)(N + 1) * 4);
    int*   cursor   = (int*)alloc((size_t)N * 4);
    int    NB       = (N + SCAN_CHUNK - 1) / SCAN_CHUNK;
    int*   bsums    = (int*)alloc((size_t)NB * 4);
    int*   bincnt   = (int*)alloc((size_t)NBINS * 4);
    int*   bstart_e = (int*)alloc((size_t)(NBINS + 1) * 4);
    int*   bincur   = (int*)alloc((size_t)NBINS * 4);
    int*   ebuf     = (int*)alloc((size_t)E * 4);
    int*   csr      = (int*)alloc(CSR_CAP * 4);
    unsigned short* h_a = (unsigned short*)alloc((size_t)(N + 1) * 64 * 2); // +sentinel row
    unsigned short* h_b = (unsigned short*)alloc((size_t)N * 64 * 2);       // bf16 agg out
    float* pooled   = (float*)alloc((size_t)G * 64 * 4);
    (void)ws_size;

    // ---- graph preprocessing ----
    hipMemsetAsync(cursor, 0, (size_t)N * 4, stream);
    hipMemsetAsync(bincnt, 0, (size_t)NBINS * 4, stream);
    hipMemsetAsync(bincur, 0, (size_t)NBINS * 4, stream);
    hipMemsetAsync(pooled, 0, (size_t)G * 64 * 4, stream);
    hipMemsetAsync(h_a + (size_t)N * 64, 0, 64 * 2, stream);   // zero sentinel row
    const int nchunks = (E + P1_CHUNK - 1) / P1_CHUNK;
    binhist_kernel<<<nchunks, 256, 0, stream>>>(dst, bincnt, E, NBINS);
    scan_small<<<1, 64, 0, stream>>>(bincnt, bstart_e, NBINS);
    phase1_kernel<<<nchunks, 256, 0, stream>>>(src, dst, bstart_e, bincur, ebuf, E, NBINS);
    bincount_kernel<<<NBINS, 256, 0, stream>>>(ebuf, bstart_e, cnt, dinvp, N);
    scan_block_sums<<<NB, 256, 0, stream>>>(cnt, bsums, N);
    scan_exclusive_bsums<<<1, 64, 0, stream>>>(bsums, NB);
    scan_write<<<NB, 256, 0, stream>>>(cnt, bsums, row_start, N);
    phase2_kernel<<<NBINS, 256, 0, stream>>>(ebuf, bstart_e, row_start, csr,
                                             cursor, N, N);

    const int nblk = (N + 3) / 4;
    const int lblk = (N + 63) / 64;
    // ---- layer 0 ----
    lin_mfma<128, false><<<lblk, 256, 0, stream>>>(x, w0, dinvp, h_a, N);
    agg_kernel<<<nblk, 256, 0, stream>>>(h_a, row_start, csr, dinvp,
                                         b0, g0, be0, m0, v0, h_b, N);
    // ---- layer 1 ----
    lin_mfma<64, true><<<lblk, 256, 0, stream>>>(h_b, w1, dinvp, h_a, N);
    agg_kernel<<<nblk, 256, 0, stream>>>(h_a, row_start, csr, dinvp,
                                         b1, g1, be1, m1, v1, h_b, N);
    // ---- layer 2 ----
    lin_mfma<64, true><<<lblk, 256, 0, stream>>>(h_b, w2, dinvp, h_a, N);
    agg_kernel<<<nblk, 256, 0, stream>>>(h_a, row_start, csr, dinvp,
                                         b2, g2, be2, m2, v2, h_b, N);
    // ---- pool + MLP ----
    const int pwaves = (N + POOL_CHUNK - 1) / POOL_CHUNK;
    pool_kernel<<<(pwaves + 3) / 4, 256, 0, stream>>>(h_b, batch, pooled, N);
    mlp_kernel<<<G, 64, 0, stream>>>(pooled, l1w, l1b, l2w, l2b, out);
}